// Round 14
// baseline (317.531 us; speedup 1.0000x reference)
//
#include <hip/hip_runtime.h>
#include <hip/hip_bf16.h>
#include <stdint.h>

typedef float f32x4 __attribute__((ext_vector_type(4)));
typedef short bf16x8 __attribute__((ext_vector_type(8)));
typedef unsigned short u16;

static constexpr int kB  = 16384;
static constexpr int kDC = 2048;
static constexpr int kNF = 768;
static constexpr float kEps = 1e-5f;

// ---- workspace layout (bytes). Region X at OFF_X reused by liveness:
//  axbf (prep->gemm1) -> H (gemmH->fuse)
static constexpr size_t OFF_FEATS  = 0;                       // [3][B][768] bf16
static constexpr size_t OFF_X      = 75497472;                // axbf 67MB / H [3*B][128] f32
static constexpr size_t OFF_WCBF   = OFF_X + 67108864;
static constexpr size_t OFF_WA1BF  = OFF_WCBF + 3145728;
static constexpr size_t OFF_W1BF   = OFF_WA1BF + 196608;
static constexpr size_t OFF_FUSE   = OFF_W1BF + 1179648;      // [B][256] f32
static constexpr size_t OFF_STATS  = OFF_FUSE + 16777216;     // 3072 (hst) + 2048 (fst)

static __device__ __forceinline__ u16 f2bf(float x) {
  union { float f; unsigned u; } c; c.f = x;
  unsigned r = c.u + 0x7fffu + ((c.u >> 16) & 1u);
  return (u16)(r >> 16);
}

static __device__ __forceinline__ unsigned pk2(float lo, float hi) {
  union { __hip_bfloat162 h; unsigned u; } c;
  c.h = __float22bfloat162_rn(make_float2(lo, hi));
  return c.u;
}

// wide convert: thread owns 4 units of 8 consecutive floats (2 adjacent float4 loads
// -> one 16B uint4 store of packed bf16). loads forced in flight via sched_barrier.
static __device__ __forceinline__ void cvtw(const float* __restrict__ in,
                                            u16* __restrict__ out, long u0) {
  float4 a[4], b[4];
#pragma unroll
  for (int i = 0; i < 4; ++i) {
    const long u = u0 + i * 256;
    a[i] = ((const float4*)in)[2 * u];
    b[i] = ((const float4*)in)[2 * u + 1];
  }
  __builtin_amdgcn_sched_barrier(0);
#pragma unroll
  for (int i = 0; i < 4; ++i) {
    const long u = u0 + i * 256;
    uint4 w;
    w.x = pk2(a[i].x, a[i].y); w.y = pk2(a[i].z, a[i].w);
    w.z = pk2(b[i].x, b[i].y); w.w = pk2(b[i].z, b[i].w);
    ((uint4*)out)[u] = w;
  }
}

// ---------------- prep: fp32 -> bf16 for xc, Wc (+ stats zero) ----------------
__global__ __launch_bounds__(256) void prep_kernel(
    const float* __restrict__ xc, const float* __restrict__ Wc,
    u16* __restrict__ axbf, u16* __restrict__ wcbf,
    float* __restrict__ stats)
{
  const int b = blockIdx.x, t = threadIdx.x;
  if (b == 4288) {           // zero 5120 B of stats (hst 3072 + fst 2048)
#pragma unroll
    for (int i = 0; i < 5; ++i) stats[t + i * 256] = 0.f;
    return;
  }
  if (b < 4096) cvtw(xc, axbf, (long)b * 1024 + t);
  else          cvtw(Wc, wcbf, (long)(b - 4096) * 1024 + t);
}

static __device__ __forceinline__ void gload16(const void* g, void* l) {
  __builtin_amdgcn_global_load_lds(
      (const __attribute__((address_space(1))) void*)g,
      (__attribute__((address_space(3))) void*)l, 16, 0, 0);
}

// ---------------- merged: GEMM1 (ctx) + converts, INTERLEAVED block ids ----------------
// 2900 blocks. Groups of 15 ids: pos 0..3 -> GEMM (192 groups x 4 = 768),
// pos 4..14 -> convert (192 x 11 = 2112); ids 2880..2899 -> converts 2112..2131.
// Interleave keeps memory-bound convert waves co-resident with GEMM blocks from t=0,
// so the GEMM's per-K-step barrier drains hide under convert traffic (R6 mechanism).
__global__ __launch_bounds__(256) void gemm_ctx_conv(
    const u16* __restrict__ A, const u16* __restrict__ B,
    const float* __restrict__ bias, u16* __restrict__ C,
    const float* __restrict__ xb, const float* __restrict__ xf,
    const float* __restrict__ Wa1, const float* __restrict__ W1,
    u16* __restrict__ feats, u16* __restrict__ wa1bf, u16* __restrict__ w1bf)
{
  __shared__ __align__(16) u16 As[128 * 32];
  __shared__ __align__(16) u16 Bs[128 * 32];
  const int id = blockIdx.x, t = threadIdx.x;

  int gemmId = -1, convId;
  if (id < 2880) {
    const int grp = id / 15, pos = id % 15;
    if (pos < 4) gemmId = grp * 4 + pos;
    else         convId = grp * 11 + (pos - 4);
  } else {
    convId = 2112 + (id - 2880);
  }

  if (gemmId < 0) {
    const int c = convId;
    if (c < 1536) {                       // xb -> feats[1]
      cvtw(xb, feats + (size_t)kB * kNF, (long)c * 1024 + t);
    } else if (c < 2048) {                // xf -> feats[2] with repeat(3)
      const long base = (long)(c - 1536) * 1024 + t;
      float4 a[4], bb4[4];
#pragma unroll
      for (int i = 0; i < 4; ++i) {
        const long u = base + i * 256;
        a[i]   = ((const float4*)xf)[2 * u];
        bb4[i] = ((const float4*)xf)[2 * u + 1];
      }
      __builtin_amdgcn_sched_barrier(0);
#pragma unroll
      for (int i = 0; i < 4; ++i) {
        const long u = base + i * 256;
        const size_t row = (size_t)(u >> 5);
        const int col = (int)(u & 31) * 8;
        const float ax = a[i].x, ay = a[i].y, az = a[i].z, aw = a[i].w;
        const float bx = bb4[i].x, by = bb4[i].y, bz = bb4[i].z, bw = bb4[i].w;
        uint4* o = (uint4*)(feats + (size_t)2 * kB * kNF + row * kNF + (size_t)col * 3);
        uint4 w0, w1, w2;
        w0.x = pk2(ax, ax); w0.y = pk2(ax, ay); w0.z = pk2(ay, ay); w0.w = pk2(az, az);
        w1.x = pk2(az, aw); w1.y = pk2(aw, aw); w1.z = pk2(bx, bx); w1.w = pk2(bx, by);
        w2.x = pk2(by, by); w2.y = pk2(bz, bz); w2.z = pk2(bz, bw); w2.w = pk2(bw, bw);
        o[0] = w0; o[1] = w1; o[2] = w2;
      }
    } else if (c < 2060) {                // Wa1 -> bf16
      cvtw(Wa1, wa1bf, (long)(c - 2048) * 1024 + t);
    } else {                              // W1 -> bf16
      cvtw(W1, w1bf, (long)(c - 2060) * 1024 + t);
    }
    return;
  }

  // ---- GEMM path: m97 structure (verified 91us config), C = A @ B^T + bias -> bf16 ----
  const int bx = gemmId & 127, by = gemmId >> 7;
  const size_t m0 = (size_t)bx * 128;
  const int n0 = by * 128;
  const int lane = t & 63, wave = t >> 6;
  const int wm = (wave >> 1) * 64, wn = (wave & 1) * 64;
  const int fr = lane & 15, fq = lane >> 4;

  const int srow = t >> 2, scol = (t & 3) * 8;
  const u16* ga0 = A + (m0 + srow) * (size_t)kDC + scol;
  const u16* ga1 = A + (m0 + 64 + srow) * (size_t)kDC + scol;
  const u16* gb0 = B + (size_t)(n0 + srow) * kDC + scol;
  const u16* gb1 = B + (size_t)(n0 + 64 + srow) * kDC + scol;
  u16* la = As + t * 8;
  u16* lb = Bs + t * 8;
  const u16* fa = As + (wm + fr) * 32 + fq * 8;
  const u16* fb = Bs + (wn + fr) * 32 + fq * 8;

  f32x4 acc[4][4] = {};

  for (int k = 0; k < 64; ++k) {
    __syncthreads();
    gload16(ga0, la);
    gload16(ga1, la + 2048);
    gload16(gb0, lb);
    gload16(gb1, lb + 2048);
    ga0 += 32; ga1 += 32; gb0 += 32; gb1 += 32;
    __syncthreads();
    bf16x8 av[4], bv[4];
#pragma unroll
    for (int mf = 0; mf < 4; ++mf) av[mf] = *(const bf16x8*)(fa + mf * 512);
#pragma unroll
    for (int nf = 0; nf < 4; ++nf) bv[nf] = *(const bf16x8*)(fb + nf * 512);
#pragma unroll
    for (int mf = 0; mf < 4; ++mf)
#pragma unroll
      for (int nf = 0; nf < 4; ++nf)
        acc[mf][nf] = __builtin_amdgcn_mfma_f32_16x16x32_bf16(av[mf], bv[nf], acc[mf][nf], 0, 0, 0);
  }

#pragma unroll
  for (int mf = 0; mf < 4; ++mf) {
    const size_t rb = m0 + wm + mf * 16 + fq * 4;
#pragma unroll
    for (int nf = 0; nf < 4; ++nf) {
      const int gn = n0 + wn + nf * 16 + fr;
      const float bb = bias[gn];
#pragma unroll
      for (int rr = 0; rr < 4; ++rr)
        C[(rb + rr) * (size_t)kNF + gn] = f2bf(acc[mf][nf][rr] + bb);
    }
  }
}

// ---------------- 64x128 GEMM, dbuf 1-barrier, f32 out, fused col stats ----------------
template <int STATS>
__global__ __launch_bounds__(256) void gemm_bt64(
    const u16* __restrict__ A, int lda, const u16* __restrict__ B, int ldb,
    const float* __restrict__ bias, float* __restrict__ C, int ldc, int K,
    float* __restrict__ stats)
{
  __shared__ __align__(16) u16 As[2 * 64 * 32];
  __shared__ __align__(16) u16 Bs[2 * 128 * 32];
  const int bx = blockIdx.x, by = blockIdx.y;
  const size_t m0 = (size_t)bx * 64;
  const int n0 = by * 128;
  const int t = threadIdx.x;
  const int lane = t & 63, wave = t >> 6;
  const int wn = wave * 32;
  const int fr = lane & 15, fq = lane >> 4;

  const int srow = t >> 2, scol = (t & 3) * 8;
  const u16* ga0 = A + (m0 + srow) * (size_t)lda + scol;
  const u16* gb0 = B + (size_t)(n0 + srow) * ldb + scol;
  const u16* gb1 = B + (size_t)(n0 + 64 + srow) * ldb + scol;

  f32x4 acc[4][2] = {};

  gload16(ga0, As + t * 8);
  gload16(gb0, Bs + t * 8);
  gload16(gb1, Bs + t * 8 + 2048);
  ga0 += 32; gb0 += 32; gb1 += 32;
  __syncthreads();

  const int kt = K >> 5;
  for (int k = 0; k < kt; ++k) {
    const int cur = k & 1;
    if (k + 1 < kt) {
      u16* an = As + (cur ^ 1) * 2048;
      u16* bn = Bs + (cur ^ 1) * 4096;
      gload16(ga0, an + t * 8);
      gload16(gb0, bn + t * 8);
      gload16(gb1, bn + t * 8 + 2048);
      ga0 += 32; gb0 += 32; gb1 += 32;
    }
    const u16* fa = As + cur * 2048 + fr * 32 + fq * 8;
    const u16* fb = Bs + cur * 4096 + (wn + fr) * 32 + fq * 8;
    bf16x8 av[4], bv[2];
#pragma unroll
    for (int mf = 0; mf < 4; ++mf) av[mf] = *(const bf16x8*)(fa + mf * 512);
#pragma unroll
    for (int nf = 0; nf < 2; ++nf) bv[nf] = *(const bf16x8*)(fb + nf * 512);
#pragma unroll
    for (int mf = 0; mf < 4; ++mf)
#pragma unroll
      for (int nf = 0; nf < 2; ++nf)
        acc[mf][nf] = __builtin_amdgcn_mfma_f32_16x16x32_bf16(av[mf], bv[nf], acc[mf][nf], 0, 0, 0);
    __syncthreads();
  }

  float cs[2] = {}, cs2[2] = {};
#pragma unroll
  for (int mf = 0; mf < 4; ++mf) {
    const size_t rb = m0 + mf * 16 + fq * 4;
#pragma unroll
    for (int nf = 0; nf < 2; ++nf) {
      const int gn = n0 + wn + nf * 16 + fr;
      const float bb = bias[gn];
#pragma unroll
      for (int rr = 0; rr < 4; ++rr) {
        const float vv = acc[mf][nf][rr] + bb;
        C[(rb + rr) * (size_t)ldc + gn] = vv;
        if (STATS) { cs[nf] += vv; cs2[nf] += vv * vv; }
      }
    }
  }
  if (STATS) {
    const int f = (int)(m0 >> 14);
#pragma unroll
    for (int nf = 0; nf < 2; ++nf) {
      float s = cs[nf], s2 = cs2[nf];
      s += __shfl_down(s, 32); s2 += __shfl_down(s2, 32);
      s += __shfl_down(s, 16); s2 += __shfl_down(s2, 16);
      if (fq == 0) {
        const int gn = n0 + wn + nf * 16 + fr;
        atomicAdd(&stats[(f * 128 + gn) * 2 + 0], s);
        atomicAdd(&stats[(f * 128 + gn) * 2 + 1], s2);
      }
    }
  }
}

// ---------------- fused fuse-GEMM: per-block att scores + (f,k) pipeline + stats ----------------
__global__ __launch_bounds__(256) void gemm_fuse64(
    const u16* __restrict__ feats, const u16* __restrict__ w1,
    const float* __restrict__ H, const float* __restrict__ hst,
    const float* __restrict__ ga, const float* __restrict__ bba,
    const float* __restrict__ Wa2, const float* __restrict__ ba2,
    const float* __restrict__ b1, float* __restrict__ fuse, float* __restrict__ fstats)
{
  __shared__ __align__(16) u16 As[2 * 64 * 32];
  __shared__ __align__(16) u16 Bs[2 * 128 * 32];
  __shared__ float gm[3][128], gb[3][128], wa2s[128], sc[64][4];
  const int bx = blockIdx.x, by = blockIdx.y;
  const size_t m0 = (size_t)bx * 64;
  const int n0 = by * 128;
  const int t = threadIdx.x;
  const int lane = t & 63, wave = t >> 6;
  const int wn = wave * 32;
  const int fr = lane & 15, fq = lane >> 4;
  const int srow = t >> 2, scol = (t & 3) * 8;

  // ---- prologue: BN coefficients + per-row attention scores (rows m0..m0+63) ----
  if (t < 128) wa2s[t] = Wa2[t];
  for (int e = t; e < 384; e += 256) {
    const int f = e >> 7, c = e & 127;
    const float m = hst[e * 2] * (1.f / kB);
    const float var = hst[e * 2 + 1] * (1.f / kB) - m * m;
    const float rs = rsqrtf(var + kEps) * ga[c];
    gm[f][c] = rs;
    gb[f][c] = bba[c] - m * rs;
  }
  __syncthreads();
  {
    const int pr = t >> 2, pq = t & 3;
    const size_t prow = m0 + pr;
    float d[3];
#pragma unroll
    for (int f = 0; f < 3; ++f) {
      const float4* h4 = (const float4*)(H + ((size_t)f * kB + prow) * 128) + pq * 8;
      float part = 0.f;
#pragma unroll
      for (int j = 0; j < 8; ++j) {
        const float4 x = h4[j];
        const int c = pq * 32 + j * 4;
        const float xn0 = x.x * gm[f][c]     + gb[f][c];
        const float xn1 = x.y * gm[f][c + 1] + gb[f][c + 1];
        const float xn2 = x.z * gm[f][c + 2] + gb[f][c + 2];
        const float xn3 = x.w * gm[f][c + 3] + gb[f][c + 3];
        part += 0.5f * xn0 * (1.f + erff(xn0 * 0.70710678118f)) * wa2s[c];
        part += 0.5f * xn1 * (1.f + erff(xn1 * 0.70710678118f)) * wa2s[c + 1];
        part += 0.5f * xn2 * (1.f + erff(xn2 * 0.70710678118f)) * wa2s[c + 2];
        part += 0.5f * xn3 * (1.f + erff(xn3 * 0.70710678118f)) * wa2s[c + 3];
      }
      part += __shfl_down(part, 2);
      part += __shfl_down(part, 1);
      d[f] = part;
    }
    if (pq == 0) {
      const float b2 = ba2[0];
      float d0 = d[0] + b2, d1 = d[1] + b2, d2 = d[2] + b2;
      const float mx = fmaxf(d0, fmaxf(d1, d2));
      const float e0 = expf(d0 - mx), e1 = expf(d1 - mx), e2 = expf(d2 - mx);
      const float inv = 1.f / (e0 + e1 + e2);
      sc[pr][0] = e0 * inv; sc[pr][1] = e1 * inv; sc[pr][2] = e2 * inv;
    }
  }
  __syncthreads();

  // ---- GEMM pipeline ----
  const u16* ga0; const u16* gb0; const u16* gb1;
  auto setf = [&](int f) {
    ga0 = feats + (size_t)f * kB * kNF + (m0 + srow) * (size_t)kNF + scol;
    gb0 = w1 + f * kNF + (size_t)(n0 + srow) * 2304 + scol;
    gb1 = gb0 + (size_t)64 * 2304;
  };

  const f32x4 vzero = {};
  f32x4 acc[4][2] = {}, tot[4][2] = {};

  setf(0);
  gload16(ga0, As + t * 8);
  gload16(gb0, Bs + t * 8);
  gload16(gb1, Bs + t * 8 + 2048);
  ga0 += 32; gb0 += 32; gb1 += 32;
  int pf = 0, pk = 1;
  int ck = 0, cf = 0;
  __syncthreads();

  for (int s = 0; s < 72; ++s) {
    const int cur = s & 1;
    if (s < 71) {
      u16* an = As + (cur ^ 1) * 2048;
      u16* bn = Bs + (cur ^ 1) * 4096;
      gload16(ga0, an + t * 8);
      gload16(gb0, bn + t * 8);
      gload16(gb1, bn + t * 8 + 2048);
      if (++pk == 24) { pk = 0; ++pf; if (pf < 3) setf(pf); }
      else { ga0 += 32; gb0 += 32; gb1 += 32; }
    }
    const u16* fa = As + cur * 2048 + fr * 32 + fq * 8;
    const u16* fb = Bs + cur * 4096 + (wn + fr) * 32 + fq * 8;
    bf16x8 av[4], bv[2];
#pragma unroll
    for (int mf = 0; mf < 4; ++mf) av[mf] = *(const bf16x8*)(fa + mf * 512);
#pragma unroll
    for (int nf = 0; nf < 2; ++nf) bv[nf] = *(const bf16x8*)(fb + nf * 512);
#pragma unroll
    for (int mf = 0; mf < 4; ++mf)
#pragma unroll
      for (int nf = 0; nf < 2; ++nf)
        acc[mf][nf] = __builtin_amdgcn_mfma_f32_16x16x32_bf16(av[mf], bv[nf], acc[mf][nf], 0, 0, 0);
    if (++ck == 24) {
      ck = 0;
#pragma unroll
      for (int mf = 0; mf < 4; ++mf) {
        const int rl = mf * 16 + fq * 4;
#pragma unroll
        for (int rr = 0; rr < 4; ++rr) {
          const float sv = sc[rl + rr][cf];
#pragma unroll
          for (int nf = 0; nf < 2; ++nf) tot[mf][nf][rr] += sv * acc[mf][nf][rr];
        }
      }
#pragma unroll
      for (int mf = 0; mf < 4; ++mf)
#pragma unroll
        for (int nf = 0; nf < 2; ++nf) acc[mf][nf] = vzero;
      ++cf;
    }
    __syncthreads();
  }

  float cs[2] = {}, cs2[2] = {};
#pragma unroll
  for (int mf = 0; mf < 4; ++mf) {
    const size_t rb = m0 + mf * 16 + fq * 4;
#pragma unroll
    for (int nf = 0; nf < 2; ++nf) {
      const int gn = n0 + wn + nf * 16 + fr;
      const float bb = b1[gn];
#pragma unroll
      for (int rr = 0; rr < 4; ++rr) {
        const float vv = tot[mf][nf][rr] + bb;
        fuse[(rb + rr) * 256 + gn] = vv;
        cs[nf] += vv; cs2[nf] += vv * vv;
      }
    }
  }
#pragma unroll
  for (int nf = 0; nf < 2; ++nf) {
    float s = cs[nf], s2 = cs2[nf];
    s += __shfl_down(s, 32); s2 += __shfl_down(s2, 32);
    s += __shfl_down(s, 16); s2 += __shfl_down(s2, 16);
    if (fq == 0) {
      const int gn = n0 + wn + nf * 16 + fr;
      atomicAdd(&fstats[gn * 2 + 0], s);
      atomicAdd(&fstats[gn * 2 + 1], s2);
    }
  }
}

// ---------------- final: bn + relu + [256 -> 26] ----------------
__global__ __launch_bounds__(64) void final_kernel(
    const float* __restrict__ fuse, const float* __restrict__ fstats,
    const float* __restrict__ g1, const float* __restrict__ be1,
    const float* __restrict__ Wcat, const float* __restrict__ bcat,
    float* __restrict__ out)
{
  const int i = blockIdx.x, l = threadIdx.x;
  __shared__ float row[256];
#pragma unroll
  for (int h = 0; h < 4; ++h) {
    const int c = l + h * 64;
    const float sum = fstats[c * 2 + 0], sq = fstats[c * 2 + 1];
    const float m = sum * (1.f / kB);
    const float var = sq * (1.f / kB) - m * m;
    const float rs = rsqrtf(var + kEps);
    const float v = (fuse[(size_t)i * 256 + c] - m) * rs * g1[c] + be1[c];
    row[c] = fmaxf(v, 0.f);
  }
  __syncthreads();
  if (l < 26) {
    float acc = bcat[l];
    const float* w = Wcat + l * 256;
    for (int k2 = 0; k2 < 256; ++k2) acc += row[k2] * w[k2];
    out[(size_t)i * 26 + l] = acc;
  }
}

extern "C" void kernel_launch(void* const* d_in, const int* in_sizes, int n_in,
                              void* d_out, int out_size, void* d_ws, size_t ws_size,
                              hipStream_t stream) {
  (void)in_sizes; (void)n_in; (void)out_size; (void)ws_size;
  const float* xc   = (const float*)d_in[0];
  const float* xb   = (const float*)d_in[1];
  const float* xf   = (const float*)d_in[2];
  const float* Wc   = (const float*)d_in[3];
  const float* bc   = (const float*)d_in[4];
  const float* Wa1  = (const float*)d_in[5];
  const float* ba1  = (const float*)d_in[6];
  const float* ga   = (const float*)d_in[7];
  const float* bba  = (const float*)d_in[8];
  const float* Wa2  = (const float*)d_in[9];
  const float* ba2  = (const float*)d_in[10];
  const float* W1   = (const float*)d_in[11];
  const float* b1   = (const float*)d_in[12];
  const float* g1   = (const float*)d_in[13];
  const float* be1  = (const float*)d_in[14];
  const float* Wcat = (const float*)d_in[15];
  const float* bcat = (const float*)d_in[16];
  float* out = (float*)d_out;

  char* ws = (char*)d_ws;
  u16* feats   = (u16*)(ws + OFF_FEATS);
  u16* axbf    = (u16*)(ws + OFF_X);       // region X use #1 (xc bf16)
  float* H     = (float*)(ws + OFF_X);     // region X use #2 ([3*B][128] f32)
  u16* wcbf    = (u16*)(ws + OFF_WCBF);
  u16* wa1bf   = (u16*)(ws + OFF_WA1BF);
  u16* w1bf    = (u16*)(ws + OFF_W1BF);
  float* fuse  = (float*)(ws + OFF_FUSE);
  float* hst   = (float*)(ws + OFF_STATS);
  float* fst   = (float*)(ws + OFF_STATS + 3072);

  // xc + Wc -> bf16 (wide stores), and zero stats (block 4288)
  prep_kernel<<<4289, 256, 0, stream>>>(xc, Wc, axbf, wcbf, hst);
  // ctx GEMM (interleaved with xb/xf/Wa1/W1 conversion blocks) -> feats[0]
  gemm_ctx_conv<<<2900, 256, 0, stream>>>(axbf, wcbf, bc, feats, xb, xf, Wa1, W1,
                                          feats, wa1bf, w1bf);
  // H = feats @ Wa1^T + ba1  (M=49152, N=128, K=768) -> f32, fused column stats
  gemm_bt64<1><<<dim3(768, 1), 256, 0, stream>>>(feats, kNF, wa1bf, kNF, ba1, H, 128, kNF, hst);
  // fuse = sum_f s_f*(feat_f @ W1_f^T) + b1, scores computed in-block from H/hst
  gemm_fuse64<<<dim3(256, 2), 256, 0, stream>>>(feats, w1bf, H, hst, ga, bba, Wa2, ba2,
                                                b1, fuse, fst);
  final_kernel<<<kB, 64, 0, stream>>>(fuse, fst, g1, be1, Wcat, bcat, out);
}

// Round 15
// 284.057 us; speedup vs baseline: 1.1178x; 1.1178x over previous
//
#include <hip/hip_runtime.h>
#include <hip/hip_bf16.h>
#include <stdint.h>

typedef float f32x4 __attribute__((ext_vector_type(4)));
typedef short bf16x8 __attribute__((ext_vector_type(8)));
typedef unsigned short u16;

static constexpr int kB  = 16384;
static constexpr int kDC = 2048;
static constexpr int kNF = 768;
static constexpr float kEps = 1e-5f;

// ---- workspace layout (bytes). Region X at OFF_X reused by liveness:
//  axbf (prep->gemm1) -> H (gemmH->att)
static constexpr size_t OFF_FEATS  = 0;                       // [3][B][768] bf16
static constexpr size_t OFF_X      = 75497472;                // axbf 67MB / H [3*B][128] f32
static constexpr size_t OFF_WCBF   = OFF_X + 67108864;
static constexpr size_t OFF_WA1BF  = OFF_WCBF + 3145728;
static constexpr size_t OFF_W1BF   = OFF_WA1BF + 196608;
static constexpr size_t OFF_FUSE   = OFF_W1BF + 1179648;      // [B][256] f32
static constexpr size_t OFF_SCORES = OFF_FUSE + 16777216;     // [B][3] f32
static constexpr size_t OFF_STATS  = OFF_SCORES + 196608;     // 3072 + 2048

static __device__ __forceinline__ u16 f2bf(float x) {
  union { float f; unsigned u; } c; c.f = x;
  unsigned r = c.u + 0x7fffu + ((c.u >> 16) & 1u);
  return (u16)(r >> 16);
}

// batched convert: force all 8 loads in flight before any cvt/store
// (sched_barrier(0) pins program order; compiler was re-serializing to save VGPRs)
static __device__ __forceinline__ void cvt8x4(const float* __restrict__ in,
                                              u16* __restrict__ out, long base) {
  float4 f[8];
#pragma unroll
  for (int i = 0; i < 8; ++i) f[i] = ((const float4*)in)[base + i * 256];
  __builtin_amdgcn_sched_barrier(0);
#pragma unroll
  for (int i = 0; i < 8; ++i)
    ((ushort4*)out)[base + i * 256] =
        make_ushort4(f2bf(f[i].x), f2bf(f[i].y), f2bf(f[i].z), f2bf(f[i].w));
}

// ---------------- prep: fp32 -> bf16 for xc, Wc, Wa1, W1 (+ stats zero) ----------------
// 256 threads x 8 float4. xc 8,388,608 f4 -> 4096 blk | Wc 393,216 -> 192 | Wa1 24,576 -> 12 |
// W1 147,456 -> 72 | stats-zero -> 1   = 4373 blocks
__global__ __launch_bounds__(256) void prep_kernel(
    const float* __restrict__ xc, const float* __restrict__ Wc,
    const float* __restrict__ Wa1, const float* __restrict__ W1,
    u16* __restrict__ axbf, u16* __restrict__ wcbf,
    u16* __restrict__ wa1bf, u16* __restrict__ w1bf,
    float* __restrict__ stats)
{
  const int b = blockIdx.x, t = threadIdx.x;
  if (b == 4372) {           // zero 5120 B of stats (hst 3072 + fst 2048)
#pragma unroll
    for (int i = 0; i < 5; ++i) stats[t + i * 256] = 0.f;
    return;
  }
  const float* in; u16* out; long base;
  if (b < 4096)      { in = xc;  out = axbf;  base = (long)b * 2048 + t; }
  else if (b < 4288) { in = Wc;  out = wcbf;  base = (long)(b - 4096) * 2048 + t; }
  else if (b < 4300) { in = Wa1; out = wa1bf; base = (long)(b - 4288) * 2048 + t; }
  else               { in = W1;  out = w1bf;  base = (long)(b - 4300) * 2048 + t; }
  cvt8x4(in, out, base);
}

static __device__ __forceinline__ void gload16(const void* g, void* l) {
  __builtin_amdgcn_global_load_lds(
      (const __attribute__((address_space(1))) void*)g,
      (__attribute__((address_space(3))) void*)l, 16, 0, 0);
}

// ---------------- merged: GEMM1 (ctx) + xb/xf bf16 conversion blocks ----------------
// 1-D grid of 768 + 1536 + 512 = 2816 blocks, GEMM ids FIRST (L2 panel locality),
// converts backfill as GEMM blocks retire (verified best config, R8: 285.5us).
__global__ __launch_bounds__(256) void gemm_ctx_conv(
    const u16* __restrict__ A, const u16* __restrict__ B,
    const float* __restrict__ bias, u16* __restrict__ C,
    const float* __restrict__ xb, const float* __restrict__ xf,
    u16* __restrict__ feats)
{
  __shared__ __align__(16) u16 As[128 * 32];
  __shared__ __align__(16) u16 Bs[128 * 32];
  const int id = blockIdx.x, t = threadIdx.x;

  if (id >= 768) {
    const int c = id - 768;
    if (c < 1536) {                       // xb -> feats[1]
      cvt8x4(xb, feats + (size_t)kB * kNF, (long)c * 2048 + t);
    } else {                              // xf -> feats[2] with repeat(3)
      const long base = (long)(c - 1536) * 2048 + t;
      float4 f[8];
#pragma unroll
      for (int i = 0; i < 8; ++i) f[i] = ((const float4*)xf)[base + i * 256];
      __builtin_amdgcn_sched_barrier(0);
#pragma unroll
      for (int i = 0; i < 8; ++i) {
        const long v = base + i * 256;
        u16 e0 = f2bf(f[i].x), e1 = f2bf(f[i].y), e2 = f2bf(f[i].z), e3 = f2bf(f[i].w);
        size_t p = (size_t)v * 4;
        size_t row = p >> 8;
        int col = (int)(p & 255);
        u16* o = feats + (size_t)2 * kB * kNF + row * kNF + col * 3;
        ushort4* o4 = (ushort4*)o;
        o4[0] = make_ushort4(e0, e0, e0, e1);
        o4[1] = make_ushort4(e1, e1, e2, e2);
        o4[2] = make_ushort4(e2, e3, e3, e3);
      }
    }
    return;
  }

  // ---- GEMM path: m97 structure, C = A @ B^T + bias -> bf16 ----
  const int bx = id & 127, by = id >> 7;
  const size_t m0 = (size_t)bx * 128;
  const int n0 = by * 128;
  const int lane = t & 63, wave = t >> 6;
  const int wm = (wave >> 1) * 64, wn = (wave & 1) * 64;
  const int fr = lane & 15, fq = lane >> 4;

  const int srow = t >> 2, scol = (t & 3) * 8;
  const u16* ga0 = A + (m0 + srow) * (size_t)kDC + scol;
  const u16* ga1 = A + (m0 + 64 + srow) * (size_t)kDC + scol;
  const u16* gb0 = B + (size_t)(n0 + srow) * kDC + scol;
  const u16* gb1 = B + (size_t)(n0 + 64 + srow) * kDC + scol;
  u16* la = As + t * 8;
  u16* lb = Bs + t * 8;
  const u16* fa = As + (wm + fr) * 32 + fq * 8;
  const u16* fb = Bs + (wn + fr) * 32 + fq * 8;

  f32x4 acc[4][4] = {};

  for (int k = 0; k < 64; ++k) {
    __syncthreads();
    gload16(ga0, la);
    gload16(ga1, la + 2048);
    gload16(gb0, lb);
    gload16(gb1, lb + 2048);
    ga0 += 32; ga1 += 32; gb0 += 32; gb1 += 32;
    __syncthreads();
    bf16x8 av[4], bv[4];
#pragma unroll
    for (int mf = 0; mf < 4; ++mf) av[mf] = *(const bf16x8*)(fa + mf * 512);
#pragma unroll
    for (int nf = 0; nf < 4; ++nf) bv[nf] = *(const bf16x8*)(fb + nf * 512);
#pragma unroll
    for (int mf = 0; mf < 4; ++mf)
#pragma unroll
      for (int nf = 0; nf < 4; ++nf)
        acc[mf][nf] = __builtin_amdgcn_mfma_f32_16x16x32_bf16(av[mf], bv[nf], acc[mf][nf], 0, 0, 0);
  }

#pragma unroll
  for (int mf = 0; mf < 4; ++mf) {
    const size_t rb = m0 + wm + mf * 16 + fq * 4;
#pragma unroll
    for (int nf = 0; nf < 4; ++nf) {
      const int gn = n0 + wn + nf * 16 + fr;
      const float bb = bias[gn];
#pragma unroll
      for (int rr = 0; rr < 4; ++rr)
        C[(rb + rr) * (size_t)kNF + gn] = f2bf(acc[mf][nf][rr] + bb);
    }
  }
}

// ---------------- 64x128 GEMM, dbuf 1-barrier, f32 out, optional col stats ----------------
template <int STATS>
__global__ __launch_bounds__(256) void gemm_bt64(
    const u16* __restrict__ A, int lda, const u16* __restrict__ B, int ldb,
    const float* __restrict__ bias, float* __restrict__ C, int ldc, int K,
    float* __restrict__ stats)
{
  __shared__ __align__(16) u16 As[2 * 64 * 32];
  __shared__ __align__(16) u16 Bs[2 * 128 * 32];
  const int bx = blockIdx.x, by = blockIdx.y;
  const size_t m0 = (size_t)bx * 64;
  const int n0 = by * 128;
  const int t = threadIdx.x;
  const int lane = t & 63, wave = t >> 6;
  const int wn = wave * 32;
  const int fr = lane & 15, fq = lane >> 4;

  const int srow = t >> 2, scol = (t & 3) * 8;
  const u16* ga0 = A + (m0 + srow) * (size_t)lda + scol;
  const u16* gb0 = B + (size_t)(n0 + srow) * ldb + scol;
  const u16* gb1 = B + (size_t)(n0 + 64 + srow) * ldb + scol;

  f32x4 acc[4][2] = {};

  gload16(ga0, As + t * 8);
  gload16(gb0, Bs + t * 8);
  gload16(gb1, Bs + t * 8 + 2048);
  ga0 += 32; gb0 += 32; gb1 += 32;
  __syncthreads();

  const int kt = K >> 5;
  for (int k = 0; k < kt; ++k) {
    const int cur = k & 1;
    if (k + 1 < kt) {
      u16* an = As + (cur ^ 1) * 2048;
      u16* bn = Bs + (cur ^ 1) * 4096;
      gload16(ga0, an + t * 8);
      gload16(gb0, bn + t * 8);
      gload16(gb1, bn + t * 8 + 2048);
      ga0 += 32; gb0 += 32; gb1 += 32;
    }
    const u16* fa = As + cur * 2048 + fr * 32 + fq * 8;
    const u16* fb = Bs + cur * 4096 + (wn + fr) * 32 + fq * 8;
    bf16x8 av[4], bv[2];
#pragma unroll
    for (int mf = 0; mf < 4; ++mf) av[mf] = *(const bf16x8*)(fa + mf * 512);
#pragma unroll
    for (int nf = 0; nf < 2; ++nf) bv[nf] = *(const bf16x8*)(fb + nf * 512);
#pragma unroll
    for (int mf = 0; mf < 4; ++mf)
#pragma unroll
      for (int nf = 0; nf < 2; ++nf)
        acc[mf][nf] = __builtin_amdgcn_mfma_f32_16x16x32_bf16(av[mf], bv[nf], acc[mf][nf], 0, 0, 0);
    __syncthreads();
  }

  float cs[2] = {}, cs2[2] = {};
#pragma unroll
  for (int mf = 0; mf < 4; ++mf) {
    const size_t rb = m0 + mf * 16 + fq * 4;
#pragma unroll
    for (int nf = 0; nf < 2; ++nf) {
      const int gn = n0 + wn + nf * 16 + fr;
      const float bb = bias[gn];
#pragma unroll
      for (int rr = 0; rr < 4; ++rr) {
        const float vv = acc[mf][nf][rr] + bb;
        C[(rb + rr) * (size_t)ldc + gn] = vv;
        if (STATS) { cs[nf] += vv; cs2[nf] += vv * vv; }
      }
    }
  }
  if (STATS) {
    const int f = (int)(m0 >> 14);
#pragma unroll
    for (int nf = 0; nf < 2; ++nf) {
      float s = cs[nf], s2 = cs2[nf];
      s += __shfl_down(s, 32); s2 += __shfl_down(s2, 32);
      s += __shfl_down(s, 16); s2 += __shfl_down(s2, 16);
      if (fq == 0) {
        const int gn = n0 + wn + nf * 16 + fr;
        atomicAdd(&stats[(f * 128 + gn) * 2 + 0], s);
        atomicAdd(&stats[(f * 128 + gn) * 2 + 1], s2);
      }
    }
  }
}

// ---------------- fused fuse-GEMM: flattened (f,k) pipeline, dbuf 1-barrier ----------------
__global__ __launch_bounds__(256) void gemm_fuse64(
    const u16* __restrict__ feats, const u16* __restrict__ w1,
    const float* __restrict__ scores, const float* __restrict__ b1,
    float* __restrict__ fuse, float* __restrict__ fstats)
{
  __shared__ __align__(16) u16 As[2 * 64 * 32];
  __shared__ __align__(16) u16 Bs[2 * 128 * 32];
  const int bx = blockIdx.x, by = blockIdx.y;
  const size_t m0 = (size_t)bx * 64;
  const int n0 = by * 128;
  const int t = threadIdx.x;
  const int lane = t & 63, wave = t >> 6;
  const int wn = wave * 32;
  const int fr = lane & 15, fq = lane >> 4;
  const int srow = t >> 2, scol = (t & 3) * 8;

  const u16* ga0; const u16* gb0; const u16* gb1;
  auto setf = [&](int f) {
    ga0 = feats + (size_t)f * kB * kNF + (m0 + srow) * (size_t)kNF + scol;
    gb0 = w1 + f * kNF + (size_t)(n0 + srow) * 2304 + scol;
    gb1 = gb0 + (size_t)64 * 2304;
  };

  const f32x4 vzero = {};
  f32x4 acc[4][2] = {}, tot[4][2] = {};

  setf(0);
  gload16(ga0, As + t * 8);
  gload16(gb0, Bs + t * 8);
  gload16(gb1, Bs + t * 8 + 2048);
  ga0 += 32; gb0 += 32; gb1 += 32;
  int pf = 0, pk = 1;
  int ck = 0, cf = 0;
  __syncthreads();

  for (int s = 0; s < 72; ++s) {
    const int cur = s & 1;
    if (s < 71) {
      u16* an = As + (cur ^ 1) * 2048;
      u16* bn = Bs + (cur ^ 1) * 4096;
      gload16(ga0, an + t * 8);
      gload16(gb0, bn + t * 8);
      gload16(gb1, bn + t * 8 + 2048);
      if (++pk == 24) { pk = 0; ++pf; if (pf < 3) setf(pf); }
      else { ga0 += 32; gb0 += 32; gb1 += 32; }
    }
    const u16* fa = As + cur * 2048 + fr * 32 + fq * 8;
    const u16* fb = Bs + cur * 4096 + (wn + fr) * 32 + fq * 8;
    bf16x8 av[4], bv[2];
#pragma unroll
    for (int mf = 0; mf < 4; ++mf) av[mf] = *(const bf16x8*)(fa + mf * 512);
#pragma unroll
    for (int nf = 0; nf < 2; ++nf) bv[nf] = *(const bf16x8*)(fb + nf * 512);
#pragma unroll
    for (int mf = 0; mf < 4; ++mf)
#pragma unroll
      for (int nf = 0; nf < 2; ++nf)
        acc[mf][nf] = __builtin_amdgcn_mfma_f32_16x16x32_bf16(av[mf], bv[nf], acc[mf][nf], 0, 0, 0);
    if (++ck == 24) {
      ck = 0;
#pragma unroll
      for (int mf = 0; mf < 4; ++mf) {
        const size_t rb = m0 + mf * 16 + fq * 4;
#pragma unroll
        for (int rr = 0; rr < 4; ++rr) {
          const float sv = scores[(rb + rr) * 3 + cf];
#pragma unroll
          for (int nf = 0; nf < 2; ++nf) tot[mf][nf][rr] += sv * acc[mf][nf][rr];
        }
      }
#pragma unroll
      for (int mf = 0; mf < 4; ++mf)
#pragma unroll
        for (int nf = 0; nf < 2; ++nf) acc[mf][nf] = vzero;
      ++cf;
    }
    __syncthreads();
  }

  float cs[2] = {}, cs2[2] = {};
#pragma unroll
  for (int mf = 0; mf < 4; ++mf) {
    const size_t rb = m0 + mf * 16 + fq * 4;
#pragma unroll
    for (int nf = 0; nf < 2; ++nf) {
      const int gn = n0 + wn + nf * 16 + fr;
      const float bb = b1[gn];
#pragma unroll
      for (int rr = 0; rr < 4; ++rr) {
        const float vv = tot[mf][nf][rr] + bb;
        fuse[(rb + rr) * 256 + gn] = vv;
        cs[nf] += vv; cs2[nf] += vv * vv;
      }
    }
  }
#pragma unroll
  for (int nf = 0; nf < 2; ++nf) {
    float s = cs[nf], s2 = cs2[nf];
    s += __shfl_down(s, 32); s2 += __shfl_down(s2, 32);
    s += __shfl_down(s, 16); s2 += __shfl_down(s2, 16);
    if (fq == 0) {
      const int gn = n0 + wn + nf * 16 + fr;
      atomicAdd(&fstats[gn * 2 + 0], s);
      atomicAdd(&fstats[gn * 2 + 1], s2);
    }
  }
}

// ---------------- attention scores: bn+gelu+dot (x3) + softmax ----------------
__global__ __launch_bounds__(64) void att_kernel(
    const float* __restrict__ H, const float* __restrict__ stats,
    const float* __restrict__ ga, const float* __restrict__ bba,
    const float* __restrict__ Wa2, const float* __restrict__ ba2,
    float* __restrict__ scores)
{
  const int i = blockIdx.x, l = threadIdx.x;
  float d[3];
#pragma unroll
  for (int f = 0; f < 3; ++f) {
    float part = 0.f;
#pragma unroll
    for (int h = 0; h < 2; ++h) {
      const int c = l + h * 64;
      const float sum = stats[(f * 128 + c) * 2 + 0];
      const float sq  = stats[(f * 128 + c) * 2 + 1];
      const float m = sum * (1.f / kB);
      const float var = sq * (1.f / kB) - m * m;
      const float rs = rsqrtf(var + kEps);
      const float x = H[((size_t)f * kB + i) * 128 + c];
      const float xn = (x - m) * rs * ga[c] + bba[c];
      const float ge = 0.5f * xn * (1.f + erff(xn * 0.70710678118f));
      part += ge * Wa2[c];
    }
#pragma unroll
    for (int off = 32; off > 0; off >>= 1) part += __shfl_down(part, off);
    d[f] = part;
  }
  if (l == 0) {
    const float b2 = ba2[0];
    float d0 = d[0] + b2, d1 = d[1] + b2, d2 = d[2] + b2;
    const float mx = fmaxf(d0, fmaxf(d1, d2));
    const float e0 = expf(d0 - mx), e1 = expf(d1 - mx), e2 = expf(d2 - mx);
    const float inv = 1.f / (e0 + e1 + e2);
    scores[i * 3 + 0] = e0 * inv;
    scores[i * 3 + 1] = e1 * inv;
    scores[i * 3 + 2] = e2 * inv;
  }
}

// ---------------- final: bn + relu + [256 -> 26] ----------------
__global__ __launch_bounds__(64) void final_kernel(
    const float* __restrict__ fuse, const float* __restrict__ fstats,
    const float* __restrict__ g1, const float* __restrict__ be1,
    const float* __restrict__ Wcat, const float* __restrict__ bcat,
    float* __restrict__ out)
{
  const int i = blockIdx.x, l = threadIdx.x;
  __shared__ float row[256];
#pragma unroll
  for (int h = 0; h < 4; ++h) {
    const int c = l + h * 64;
    const float sum = fstats[c * 2 + 0], sq = fstats[c * 2 + 1];
    const float m = sum * (1.f / kB);
    const float var = sq * (1.f / kB) - m * m;
    const float rs = rsqrtf(var + kEps);
    const float v = (fuse[(size_t)i * 256 + c] - m) * rs * g1[c] + be1[c];
    row[c] = fmaxf(v, 0.f);
  }
  __syncthreads();
  if (l < 26) {
    float acc = bcat[l];
    const float* w = Wcat + l * 256;
    for (int k2 = 0; k2 < 256; ++k2) acc += row[k2] * w[k2];
    out[(size_t)i * 26 + l] = acc;
  }
}

extern "C" void kernel_launch(void* const* d_in, const int* in_sizes, int n_in,
                              void* d_out, int out_size, void* d_ws, size_t ws_size,
                              hipStream_t stream) {
  (void)in_sizes; (void)n_in; (void)out_size; (void)ws_size;
  const float* xc   = (const float*)d_in[0];
  const float* xb   = (const float*)d_in[1];
  const float* xf   = (const float*)d_in[2];
  const float* Wc   = (const float*)d_in[3];
  const float* bc   = (const float*)d_in[4];
  const float* Wa1  = (const float*)d_in[5];
  const float* ba1  = (const float*)d_in[6];
  const float* ga   = (const float*)d_in[7];
  const float* bba  = (const float*)d_in[8];
  const float* Wa2  = (const float*)d_in[9];
  const float* ba2  = (const float*)d_in[10];
  const float* W1   = (const float*)d_in[11];
  const float* b1   = (const float*)d_in[12];
  const float* g1   = (const float*)d_in[13];
  const float* be1  = (const float*)d_in[14];
  const float* Wcat = (const float*)d_in[15];
  const float* bcat = (const float*)d_in[16];
  float* out = (float*)d_out;

  char* ws = (char*)d_ws;
  u16* feats   = (u16*)(ws + OFF_FEATS);
  u16* axbf    = (u16*)(ws + OFF_X);       // region X use #1 (xc bf16)
  float* H     = (float*)(ws + OFF_X);     // region X use #2 ([3*B][128] f32)
  u16* wcbf    = (u16*)(ws + OFF_WCBF);
  u16* wa1bf   = (u16*)(ws + OFF_WA1BF);
  u16* w1bf    = (u16*)(ws + OFF_W1BF);
  float* fuse  = (float*)(ws + OFF_FUSE);
  float* scores= (float*)(ws + OFF_SCORES);
  float* hst   = (float*)(ws + OFF_STATS);
  float* fst   = (float*)(ws + OFF_STATS + 3072);

  // xc + weights -> bf16, and zero stats (block 4372)
  prep_kernel<<<4373, 256, 0, stream>>>(xc, Wc, Wa1, W1, axbf, wcbf, wa1bf, w1bf, hst);
  // ctx GEMM (M=16384,N=768,K=2048) -> feats[0], overlapped with xb/xf conversion blocks
  gemm_ctx_conv<<<2816, 256, 0, stream>>>(axbf, wcbf, bc, feats, xb, xf, feats);
  // H = feats @ Wa1^T + ba1  (M=49152, N=128, K=768) -> f32, fused column stats
  gemm_bt64<1><<<dim3(768, 1), 256, 0, stream>>>(feats, kNF, wa1bf, kNF, ba1, H, 128, kNF, hst);
  att_kernel<<<kB, 64, 0, stream>>>(H, hst, ga, bba, Wa2, ba2, scores);
  // fuse = sum_f s_f*(feat_f @ W1_f^T) + b1  (M=16384, N=256, 3x K=768), fused stats
  gemm_fuse64<<<dim3(256, 2), 256, 0, stream>>>(feats, w1bf, scores, b1, fuse, fst);
  final_kernel<<<kB, 64, 0, stream>>>(fuse, fst, g1, be1, Wcat, bcat, out);
}

// Round 17
// 282.709 us; speedup vs baseline: 1.1232x; 1.0048x over previous
//
#include <hip/hip_runtime.h>
#include <hip/hip_bf16.h>
#include <stdint.h>

typedef float f32x4 __attribute__((ext_vector_type(4)));
typedef short bf16x8 __attribute__((ext_vector_type(8)));
typedef unsigned short u16;

static constexpr int kB  = 16384;
static constexpr int kDC = 2048;
static constexpr int kNF = 768;
static constexpr float kEps = 1e-5f;

// ---- workspace layout (bytes). Region X at OFF_X reused by liveness:
//  axbf (prep->gemm1) -> H (gemmH->att)
static constexpr size_t OFF_FEATS  = 0;                       // [3][B][768] bf16
static constexpr size_t OFF_X      = 75497472;                // axbf 67MB / H [3*B][128] f32
static constexpr size_t OFF_WCBF   = OFF_X + 67108864;
static constexpr size_t OFF_WA1BF  = OFF_WCBF + 3145728;
static constexpr size_t OFF_W1BF   = OFF_WA1BF + 196608;
static constexpr size_t OFF_FUSE   = OFF_W1BF + 1179648;      // [B][256] f32
static constexpr size_t OFF_SCORES = OFF_FUSE + 16777216;     // [B][3] f32
static constexpr size_t OFF_STATS  = OFF_SCORES + 196608;     // 3072 + 2048

static __device__ __forceinline__ u16 f2bf(float x) {
  union { float f; unsigned u; } c; c.f = x;
  unsigned r = c.u + 0x7fffu + ((c.u >> 16) & 1u);
  return (u16)(r >> 16);
}

// batched convert, nt streaming reads: all 8 loads in flight before any cvt/store
static __device__ __forceinline__ void cvt8x4(const float* __restrict__ in,
                                              u16* __restrict__ out, long base) {
  f32x4 f[8];
#pragma unroll
  for (int i = 0; i < 8; ++i)
    f[i] = __builtin_nontemporal_load(((const f32x4*)in) + base + i * 256);
  __builtin_amdgcn_sched_barrier(0);
#pragma unroll
  for (int i = 0; i < 8; ++i)
    ((ushort4*)out)[base + i * 256] =
        make_ushort4(f2bf(f[i].x), f2bf(f[i].y), f2bf(f[i].z), f2bf(f[i].w));
}

// ---------------- prep: fp32 -> bf16 for xc, Wc, Wa1, W1 (+ stats zero) ----------------
// 256 threads x 8 float4. xc 8,388,608 f4 -> 4096 blk | Wc 393,216 -> 192 | Wa1 24,576 -> 12 |
// W1 147,456 -> 72 | stats-zero -> 1   = 4373 blocks
__global__ __launch_bounds__(256) void prep_kernel(
    const float* __restrict__ xc, const float* __restrict__ Wc,
    const float* __restrict__ Wa1, const float* __restrict__ W1,
    u16* __restrict__ axbf, u16* __restrict__ wcbf,
    u16* __restrict__ wa1bf, u16* __restrict__ w1bf,
    float* __restrict__ stats)
{
  const int b = blockIdx.x, t = threadIdx.x;
  if (b == 4372) {           // zero 5120 B of stats (hst 3072 + fst 2048)
#pragma unroll
    for (int i = 0; i < 5; ++i) stats[t + i * 256] = 0.f;
    return;
  }
  const float* in; u16* out; long base;
  if (b < 4096)      { in = xc;  out = axbf;  base = (long)b * 2048 + t; }
  else if (b < 4288) { in = Wc;  out = wcbf;  base = (long)(b - 4096) * 2048 + t; }
  else if (b < 4300) { in = Wa1; out = wa1bf; base = (long)(b - 4288) * 2048 + t; }
  else               { in = W1;  out = w1bf;  base = (long)(b - 4300) * 2048 + t; }
  cvt8x4(in, out, base);
}

static __device__ __forceinline__ void gload16(const void* g, void* l) {
  __builtin_amdgcn_global_load_lds(
      (const __attribute__((address_space(1))) void*)g,
      (__attribute__((address_space(3))) void*)l, 16, 0, 0);
}

// ---------------- merged: GEMM1 (ctx) + xb/xf bf16 conversion blocks ----------------
// 1-D grid of 768 + 1536 + 512 = 2816 blocks, GEMM ids FIRST (L2 panel locality),
// converts backfill as GEMM blocks retire (verified best config, R8/R15: 284-285.5us).
__global__ __launch_bounds__(256) void gemm_ctx_conv(
    const u16* __restrict__ A, const u16* __restrict__ B,
    const float* __restrict__ bias, u16* __restrict__ C,
    const float* __restrict__ xb, const float* __restrict__ xf,
    u16* __restrict__ feats)
{
  __shared__ __align__(16) u16 As[128 * 32];
  __shared__ __align__(16) u16 Bs[128 * 32];
  const int id = blockIdx.x, t = threadIdx.x;

  if (id >= 768) {
    const int c = id - 768;
    if (c < 1536) {                       // xb -> feats[1]
      cvt8x4(xb, feats + (size_t)kB * kNF, (long)c * 2048 + t);
    } else {                              // xf -> feats[2] with repeat(3)
      const long base = (long)(c - 1536) * 2048 + t;
      f32x4 f[8];
#pragma unroll
      for (int i = 0; i < 8; ++i)
        f[i] = __builtin_nontemporal_load(((const f32x4*)xf) + base + i * 256);
      __builtin_amdgcn_sched_barrier(0);
#pragma unroll
      for (int i = 0; i < 8; ++i) {
        const long v = base + i * 256;
        u16 e0 = f2bf(f[i].x), e1 = f2bf(f[i].y), e2 = f2bf(f[i].z), e3 = f2bf(f[i].w);
        size_t p = (size_t)v * 4;
        size_t row = p >> 8;
        int col = (int)(p & 255);
        u16* o = feats + (size_t)2 * kB * kNF + row * kNF + col * 3;
        ushort4* o4 = (ushort4*)o;
        o4[0] = make_ushort4(e0, e0, e0, e1);
        o4[1] = make_ushort4(e1, e1, e2, e2);
        o4[2] = make_ushort4(e2, e3, e3, e3);
      }
    }
    return;
  }

  // ---- GEMM path: m97 structure, C = A @ B^T + bias -> bf16 ----
  const int bx = id & 127, by = id >> 7;
  const size_t m0 = (size_t)bx * 128;
  const int n0 = by * 128;
  const int lane = t & 63, wave = t >> 6;
  const int wm = (wave >> 1) * 64, wn = (wave & 1) * 64;
  const int fr = lane & 15, fq = lane >> 4;

  const int srow = t >> 2, scol = (t & 3) * 8;
  const u16* ga0 = A + (m0 + srow) * (size_t)kDC + scol;
  const u16* ga1 = A + (m0 + 64 + srow) * (size_t)kDC + scol;
  const u16* gb0 = B + (size_t)(n0 + srow) * kDC + scol;
  const u16* gb1 = B + (size_t)(n0 + 64 + srow) * kDC + scol;
  u16* la = As + t * 8;
  u16* lb = Bs + t * 8;
  const u16* fa = As + (wm + fr) * 32 + fq * 8;
  const u16* fb = Bs + (wn + fr) * 32 + fq * 8;

  f32x4 acc[4][4] = {};

  for (int k = 0; k < 64; ++k) {
    __syncthreads();
    gload16(ga0, la);
    gload16(ga1, la + 2048);
    gload16(gb0, lb);
    gload16(gb1, lb + 2048);
    ga0 += 32; ga1 += 32; gb0 += 32; gb1 += 32;
    __syncthreads();
    bf16x8 av[4], bv[4];
#pragma unroll
    for (int mf = 0; mf < 4; ++mf) av[mf] = *(const bf16x8*)(fa + mf * 512);
#pragma unroll
    for (int nf = 0; nf < 4; ++nf) bv[nf] = *(const bf16x8*)(fb + nf * 512);
#pragma unroll
    for (int mf = 0; mf < 4; ++mf)
#pragma unroll
      for (int nf = 0; nf < 4; ++nf)
        acc[mf][nf] = __builtin_amdgcn_mfma_f32_16x16x32_bf16(av[mf], bv[nf], acc[mf][nf], 0, 0, 0);
  }

#pragma unroll
  for (int mf = 0; mf < 4; ++mf) {
    const size_t rb = m0 + wm + mf * 16 + fq * 4;
#pragma unroll
    for (int nf = 0; nf < 4; ++nf) {
      const int gn = n0 + wn + nf * 16 + fr;
      const float bb = bias[gn];
#pragma unroll
      for (int rr = 0; rr < 4; ++rr)
        C[(rb + rr) * (size_t)kNF + gn] = f2bf(acc[mf][nf][rr] + bb);
    }
  }
}

// ---------------- 64x128 GEMM, dbuf 1-barrier, f32 out, optional col stats ----------------
template <int STATS>
__global__ __launch_bounds__(256) void gemm_bt64(
    const u16* __restrict__ A, int lda, const u16* __restrict__ B, int ldb,
    const float* __restrict__ bias, float* __restrict__ C, int ldc, int K,
    float* __restrict__ stats)
{
  __shared__ __align__(16) u16 As[2 * 64 * 32];
  __shared__ __align__(16) u16 Bs[2 * 128 * 32];
  const int bx = blockIdx.x, by = blockIdx.y;
  const size_t m0 = (size_t)bx * 64;
  const int n0 = by * 128;
  const int t = threadIdx.x;
  const int lane = t & 63, wave = t >> 6;
  const int wn = wave * 32;
  const int fr = lane & 15, fq = lane >> 4;

  const int srow = t >> 2, scol = (t & 3) * 8;
  const u16* ga0 = A + (m0 + srow) * (size_t)lda + scol;
  const u16* gb0 = B + (size_t)(n0 + srow) * ldb + scol;
  const u16* gb1 = B + (size_t)(n0 + 64 + srow) * ldb + scol;

  f32x4 acc[4][2] = {};

  gload16(ga0, As + t * 8);
  gload16(gb0, Bs + t * 8);
  gload16(gb1, Bs + t * 8 + 2048);
  ga0 += 32; gb0 += 32; gb1 += 32;
  __syncthreads();

  const int kt = K >> 5;
  for (int k = 0; k < kt; ++k) {
    const int cur = k & 1;
    if (k + 1 < kt) {
      u16* an = As + (cur ^ 1) * 2048;
      u16* bn = Bs + (cur ^ 1) * 4096;
      gload16(ga0, an + t * 8);
      gload16(gb0, bn + t * 8);
      gload16(gb1, bn + t * 8 + 2048);
      ga0 += 32; gb0 += 32; gb1 += 32;
    }
    const u16* fa = As + cur * 2048 + fr * 32 + fq * 8;
    const u16* fb = Bs + cur * 4096 + (wn + fr) * 32 + fq * 8;
    bf16x8 av[4], bv[2];
#pragma unroll
    for (int mf = 0; mf < 4; ++mf) av[mf] = *(const bf16x8*)(fa + mf * 512);
#pragma unroll
    for (int nf = 0; nf < 2; ++nf) bv[nf] = *(const bf16x8*)(fb + nf * 512);
#pragma unroll
    for (int mf = 0; mf < 4; ++mf)
#pragma unroll
      for (int nf = 0; nf < 2; ++nf)
        acc[mf][nf] = __builtin_amdgcn_mfma_f32_16x16x32_bf16(av[mf], bv[nf], acc[mf][nf], 0, 0, 0);
    __syncthreads();
  }

  float cs[2] = {}, cs2[2] = {};
#pragma unroll
  for (int mf = 0; mf < 4; ++mf) {
    const size_t rb = m0 + mf * 16 + fq * 4;
#pragma unroll
    for (int nf = 0; nf < 2; ++nf) {
      const int gn = n0 + wn + nf * 16 + fr;
      const float bb = bias[gn];
#pragma unroll
      for (int rr = 0; rr < 4; ++rr) {
        const float vv = acc[mf][nf][rr] + bb;
        C[(rb + rr) * (size_t)ldc + gn] = vv;
        if (STATS) { cs[nf] += vv; cs2[nf] += vv * vv; }
      }
    }
  }
  if (STATS) {
    const int f = (int)(m0 >> 14);
#pragma unroll
    for (int nf = 0; nf < 2; ++nf) {
      float s = cs[nf], s2 = cs2[nf];
      s += __shfl_down(s, 32); s2 += __shfl_down(s2, 32);
      s += __shfl_down(s, 16); s2 += __shfl_down(s2, 16);
      if (fq == 0) {
        const int gn = n0 + wn + nf * 16 + fr;
        atomicAdd(&stats[(f * 128 + gn) * 2 + 0], s);
        atomicAdd(&stats[(f * 128 + gn) * 2 + 1], s2);
      }
    }
  }
}

// ---------------- fused fuse-GEMM: flattened (f,k) pipeline, dbuf 1-barrier ----------------
__global__ __launch_bounds__(256) void gemm_fuse64(
    const u16* __restrict__ feats, const u16* __restrict__ w1,
    const float* __restrict__ scores, const float* __restrict__ b1,
    float* __restrict__ fuse, float* __restrict__ fstats)
{
  __shared__ __align__(16) u16 As[2 * 64 * 32];
  __shared__ __align__(16) u16 Bs[2 * 128 * 32];
  const int bx = blockIdx.x, by = blockIdx.y;
  const size_t m0 = (size_t)bx * 64;
  const int n0 = by * 128;
  const int t = threadIdx.x;
  const int lane = t & 63, wave = t >> 6;
  const int wn = wave * 32;
  const int fr = lane & 15, fq = lane >> 4;
  const int srow = t >> 2, scol = (t & 3) * 8;

  const u16* ga0; const u16* gb0; const u16* gb1;
  auto setf = [&](int f) {
    ga0 = feats + (size_t)f * kB * kNF + (m0 + srow) * (size_t)kNF + scol;
    gb0 = w1 + f * kNF + (size_t)(n0 + srow) * 2304 + scol;
    gb1 = gb0 + (size_t)64 * 2304;
  };

  const f32x4 vzero = {};
  f32x4 acc[4][2] = {}, tot[4][2] = {};

  setf(0);
  gload16(ga0, As + t * 8);
  gload16(gb0, Bs + t * 8);
  gload16(gb1, Bs + t * 8 + 2048);
  ga0 += 32; gb0 += 32; gb1 += 32;
  int pf = 0, pk = 1;
  int ck = 0, cf = 0;
  __syncthreads();

  for (int s = 0; s < 72; ++s) {
    const int cur = s & 1;
    if (s < 71) {
      u16* an = As + (cur ^ 1) * 2048;
      u16* bn = Bs + (cur ^ 1) * 4096;
      gload16(ga0, an + t * 8);
      gload16(gb0, bn + t * 8);
      gload16(gb1, bn + t * 8 + 2048);
      if (++pk == 24) { pk = 0; ++pf; if (pf < 3) setf(pf); }
      else { ga0 += 32; gb0 += 32; gb1 += 32; }
    }
    const u16* fa = As + cur * 2048 + fr * 32 + fq * 8;
    const u16* fb = Bs + cur * 4096 + (wn + fr) * 32 + fq * 8;
    bf16x8 av[4], bv[2];
#pragma unroll
    for (int mf = 0; mf < 4; ++mf) av[mf] = *(const bf16x8*)(fa + mf * 512);
#pragma unroll
    for (int nf = 0; nf < 2; ++nf) bv[nf] = *(const bf16x8*)(fb + nf * 512);
#pragma unroll
    for (int mf = 0; mf < 4; ++mf)
#pragma unroll
      for (int nf = 0; nf < 2; ++nf)
        acc[mf][nf] = __builtin_amdgcn_mfma_f32_16x16x32_bf16(av[mf], bv[nf], acc[mf][nf], 0, 0, 0);
    if (++ck == 24) {
      ck = 0;
#pragma unroll
      for (int mf = 0; mf < 4; ++mf) {
        const size_t rb = m0 + mf * 16 + fq * 4;
#pragma unroll
        for (int rr = 0; rr < 4; ++rr) {
          const float sv = scores[(rb + rr) * 3 + cf];
#pragma unroll
          for (int nf = 0; nf < 2; ++nf) tot[mf][nf][rr] += sv * acc[mf][nf][rr];
        }
      }
#pragma unroll
      for (int mf = 0; mf < 4; ++mf)
#pragma unroll
        for (int nf = 0; nf < 2; ++nf) acc[mf][nf] = vzero;
      ++cf;
    }
    __syncthreads();
  }

  float cs[2] = {}, cs2[2] = {};
#pragma unroll
  for (int mf = 0; mf < 4; ++mf) {
    const size_t rb = m0 + mf * 16 + fq * 4;
#pragma unroll
    for (int nf = 0; nf < 2; ++nf) {
      const int gn = n0 + wn + nf * 16 + fr;
      const float bb = b1[gn];
#pragma unroll
      for (int rr = 0; rr < 4; ++rr) {
        const float vv = tot[mf][nf][rr] + bb;
        fuse[(rb + rr) * 256 + gn] = vv;
        cs[nf] += vv; cs2[nf] += vv * vv;
      }
    }
  }
#pragma unroll
  for (int nf = 0; nf < 2; ++nf) {
    float s = cs[nf], s2 = cs2[nf];
    s += __shfl_down(s, 32); s2 += __shfl_down(s2, 32);
    s += __shfl_down(s, 16); s2 += __shfl_down(s2, 16);
    if (fq == 0) {
      const int gn = n0 + wn + nf * 16 + fr;
      atomicAdd(&fstats[gn * 2 + 0], s);
      atomicAdd(&fstats[gn * 2 + 1], s2);
    }
  }
}

// ---------------- attention scores: bn+gelu+dot (x3) + softmax ----------------
__global__ __launch_bounds__(64) void att_kernel(
    const float* __restrict__ H, const float* __restrict__ stats,
    const float* __restrict__ ga, const float* __restrict__ bba,
    const float* __restrict__ Wa2, const float* __restrict__ ba2,
    float* __restrict__ scores)
{
  const int i = blockIdx.x, l = threadIdx.x;
  float d[3];
#pragma unroll
  for (int f = 0; f < 3; ++f) {
    float part = 0.f;
#pragma unroll
    for (int h = 0; h < 2; ++h) {
      const int c = l + h * 64;
      const float sum = stats[(f * 128 + c) * 2 + 0];
      const float sq  = stats[(f * 128 + c) * 2 + 1];
      const float m = sum * (1.f / kB);
      const float var = sq * (1.f / kB) - m * m;
      const float rs = rsqrtf(var + kEps);
      const float x = H[((size_t)f * kB + i) * 128 + c];
      const float xn = (x - m) * rs * ga[c] + bba[c];
      const float ge = 0.5f * xn * (1.f + erff(xn * 0.70710678118f));
      part += ge * Wa2[c];
    }
#pragma unroll
    for (int off = 32; off > 0; off >>= 1) part += __shfl_down(part, off);
    d[f] = part;
  }
  if (l == 0) {
    const float b2 = ba2[0];
    float d0 = d[0] + b2, d1 = d[1] + b2, d2 = d[2] + b2;
    const float mx = fmaxf(d0, fmaxf(d1, d2));
    const float e0 = expf(d0 - mx), e1 = expf(d1 - mx), e2 = expf(d2 - mx);
    const float inv = 1.f / (e0 + e1 + e2);
    scores[i * 3 + 0] = e0 * inv;
    scores[i * 3 + 1] = e1 * inv;
    scores[i * 3 + 2] = e2 * inv;
  }
}

// ---------------- final: bn + relu + [256 -> 26] ----------------
__global__ __launch_bounds__(64) void final_kernel(
    const float* __restrict__ fuse, const float* __restrict__ fstats,
    const float* __restrict__ g1, const float* __restrict__ be1,
    const float* __restrict__ Wcat, const float* __restrict__ bcat,
    float* __restrict__ out)
{
  const int i = blockIdx.x, l = threadIdx.x;
  __shared__ float row[256];
#pragma unroll
  for (int h = 0; h < 4; ++h) {
    const int c = l + h * 64;
    const float sum = fstats[c * 2 + 0], sq = fstats[c * 2 + 1];
    const float m = sum * (1.f / kB);
    const float var = sq * (1.f / kB) - m * m;
    const float rs = rsqrtf(var + kEps);
    const float v = (fuse[(size_t)i * 256 + c] - m) * rs * g1[c] + be1[c];
    row[c] = fmaxf(v, 0.f);
  }
  __syncthreads();
  if (l < 26) {
    float acc = bcat[l];
    const float* w = Wcat + l * 256;
    for (int k2 = 0; k2 < 256; ++k2) acc += row[k2] * w[k2];
    out[(size_t)i * 26 + l] = acc;
  }
}

extern "C" void kernel_launch(void* const* d_in, const int* in_sizes, int n_in,
                              void* d_out, int out_size, void* d_ws, size_t ws_size,
                              hipStream_t stream) {
  (void)in_sizes; (void)n_in; (void)out_size; (void)ws_size;
  const float* xc   = (const float*)d_in[0];
  const float* xb   = (const float*)d_in[1];
  const float* xf   = (const float*)d_in[2];
  const float* Wc   = (const float*)d_in[3];
  const float* bc   = (const float*)d_in[4];
  const float* Wa1  = (const float*)d_in[5];
  const float* ba1  = (const float*)d_in[6];
  const float* ga   = (const float*)d_in[7];
  const float* bba  = (const float*)d_in[8];
  const float* Wa2  = (const float*)d_in[9];
  const float* ba2  = (const float*)d_in[10];
  const float* W1   = (const float*)d_in[11];
  const float* b1   = (const float*)d_in[12];
  const float* g1   = (const float*)d_in[13];
  const float* be1  = (const float*)d_in[14];
  const float* Wcat = (const float*)d_in[15];
  const float* bcat = (const float*)d_in[16];
  float* out = (float*)d_out;

  char* ws = (char*)d_ws;
  u16* feats   = (u16*)(ws + OFF_FEATS);
  u16* axbf    = (u16*)(ws + OFF_X);       // region X use #1 (xc bf16)
  float* H     = (float*)(ws + OFF_X);     // region X use #2 ([3*B][128] f32)
  u16* wcbf    = (u16*)(ws + OFF_WCBF);
  u16* wa1bf   = (u16*)(ws + OFF_WA1BF);
  u16* w1bf    = (u16*)(ws + OFF_W1BF);
  float* fuse  = (float*)(ws + OFF_FUSE);
  float* scores= (float*)(ws + OFF_SCORES);
  float* hst   = (float*)(ws + OFF_STATS);
  float* fst   = (float*)(ws + OFF_STATS + 3072);

  // xc + weights -> bf16 (nt streaming reads), and zero stats (block 4372)
  prep_kernel<<<4373, 256, 0, stream>>>(xc, Wc, Wa1, W1, axbf, wcbf, wa1bf, w1bf, hst);
  // ctx GEMM (M=16384,N=768,K=2048) -> feats[0], overlapped with xb/xf conversion blocks
  gemm_ctx_conv<<<2816, 256, 0, stream>>>(axbf, wcbf, bc, feats, xb, xf, feats);
  // H = feats @ Wa1^T + ba1  (M=49152, N=128, K=768) -> f32, fused column stats
  gemm_bt64<1><<<dim3(768, 1), 256, 0, stream>>>(feats, kNF, wa1bf, kNF, ba1, H, 128, kNF, hst);
  att_kernel<<<kB, 64, 0, stream>>>(H, hst, ga, bba, Wa2, ba2, scores);
  // fuse = sum_f s_f*(feat_f @ W1_f^T) + b1  (M=16384, N=256, 3x K=768), fused stats
  gemm_fuse64<<<dim3(256, 2), 256, 0, stream>>>(feats, w1bf, scores, b1, fuse, fst);
  final_kernel<<<kB, 64, 0, stream>>>(fuse, fst, g1, be1, Wcat, bcat, out);
}